// Round 5
// baseline (257.130 us; speedup 1.0000x reference)
//
#include <hip/hip_runtime.h>
#include <hip/hip_bf16.h>

#define BS 4
#define NQ 6000
#define NV 13294
#define NH 8
#define HD 32
#define EMB 256
#define MV (BS * NV)  // 53176
#define MQ (BS * NQ)  // 24000

typedef __attribute__((ext_vector_type(8))) short short8;
typedef __attribute__((ext_vector_type(4))) float floatx4;

__device__ __constant__ float LVL_DIM[4] = {100.f, 50.f, 25.f, 13.f};

__device__ inline unsigned short bf16bits(float f) {
  __hip_bfloat16 h = __float2bfloat16(f);
  return *reinterpret_cast<unsigned short*>(&h);
}
__device__ inline unsigned int pk2bf(float lo, float hi) {
  return (unsigned int)bf16bits(lo) | ((unsigned int)bf16bits(hi) << 16);
}
__device__ inline float bflo(unsigned int u) { return __uint_as_float(u << 16); }
__device__ inline float bfhi(unsigned int u) { return __uint_as_float(u & 0xffff0000u); }

// BK=32 tile rows: 32 bf16 = 64 B, padded to 80 B (LDSTR=40 shorts).
// 80 B is 16-byte aligned for every row -> real ds_read_b128/ds_write_b128.
// (R3 lesson: LDSTR=36 = 72 B broke 16B alignment -> split DS ops, +33 us.)
#define LDSTR 40
#define TILEU (128 * LDSTR)
// Output-tile staging stride (shorts): 136 = 128 + 8 pad; 272 B/row keeps
// 16-B alignment and breaks the 4-row quad stride off bank-multiples.
#define OSTR 136

// ---------------------------------------------------------------------------
// Coalesced tiled weight transpose + bf16 convert: Wt[n][k] = bf16(W[k][n]).
// ---------------------------------------------------------------------------
__global__ __launch_bounds__(256) void wtrans_kernel(
    const float* __restrict__ W_val, const float* __restrict__ W_off,
    const float* __restrict__ W_attn, const float* __restrict__ W_out,
    unsigned short* __restrict__ Wt_val, unsigned short* __restrict__ Wt_qcat,
    unsigned short* __restrict__ Wt_out) {
  __shared__ float tile[32][33];
  const int b = blockIdx.x;
  const int x = threadIdx.x & 31, ty = threadIdx.x >> 5;  // ty in [0,8)

  const float* src;
  unsigned short* dst;
  int k0, n0;  // src is [K=256][N], tile at (k0, n0); dst row = n, col = k
  if (b < 64) {
    src = W_val;
    dst = Wt_val;
    k0 = (b >> 3) * 32;
    n0 = (b & 7) * 32;
  } else if (b < 128) {
    const int bb = b - 64;
    src = W_off;
    dst = Wt_qcat;
    k0 = (bb >> 3) * 32;
    n0 = (bb & 7) * 32;
  } else if (b < 160) {
    const int bb = b - 128;  // W_attn: 256x128, tiles 8x4
    src = W_attn;
    dst = Wt_qcat + 256 * EMB;
    k0 = (bb >> 2) * 32;
    n0 = (bb & 3) * 32;
#pragma unroll
    for (int i = 0; i < 4; ++i)
      tile[ty + 8 * i][x] = src[(size_t)(k0 + ty + 8 * i) * 128 + n0 + x];
    __syncthreads();
#pragma unroll
    for (int i = 0; i < 4; ++i)
      dst[(size_t)(n0 + ty + 8 * i) * EMB + k0 + x] =
          bf16bits(tile[x][ty + 8 * i]);
    return;
  } else {
    const int bb = b - 160;
    src = W_out;
    dst = Wt_out;
    k0 = (bb >> 3) * 32;
    n0 = (bb & 7) * 32;
  }
#pragma unroll
  for (int i = 0; i < 4; ++i)
    tile[ty + 8 * i][x] = src[(size_t)(k0 + ty + 8 * i) * 256 + n0 + x];
  __syncthreads();
#pragma unroll
  for (int i = 0; i < 4; ++i)
    dst[(size_t)(n0 + ty + 8 * i) * EMB + k0 + x] = bf16bits(tile[x][ty + 8 * i]);
}

// ---------------------------------------------------------------------------
// MFMA-GEMM core: 128x128 tile, 4 waves (64x64 each), BK=32 (8 K-iters),
// double-buffered LDS, __syncthreads per K-iter, 2-deep register prefetch.
// ---------------------------------------------------------------------------
__device__ inline void loadA32(const float* __restrict__ A, int M, int m0,
                               int k0, int tid, float4 ra[4]) {
  const int r = tid >> 1, kh = (tid & 1) * 16;
  const int row = m0 + r;
  if (row < M) {
    const float* src = A + (size_t)row * EMB + k0 + kh;
#pragma unroll
    for (int j = 0; j < 4; ++j) ra[j] = *(const float4*)(src + 4 * j);
  } else {
#pragma unroll
    for (int j = 0; j < 4; ++j) ra[j] = make_float4(0.f, 0.f, 0.f, 0.f);
  }
}
__device__ inline void storeA32(unsigned short* lds, int tid,
                                const float4 ra[4]) {
  const int r = tid >> 1, kh = (tid & 1) * 16;
  unsigned short* dst = lds + r * LDSTR + kh;
  uint4 u0, u1;
  u0.x = pk2bf(ra[0].x, ra[0].y);
  u0.y = pk2bf(ra[0].z, ra[0].w);
  u0.z = pk2bf(ra[1].x, ra[1].y);
  u0.w = pk2bf(ra[1].z, ra[1].w);
  u1.x = pk2bf(ra[2].x, ra[2].y);
  u1.y = pk2bf(ra[2].z, ra[2].w);
  u1.z = pk2bf(ra[3].x, ra[3].y);
  u1.w = pk2bf(ra[3].z, ra[3].w);
  *(uint4*)(dst) = u0;
  *(uint4*)(dst + 8) = u1;
}
__device__ inline void loadBb(const unsigned short* __restrict__ B, int NB,
                              int n0, int k0, int tid, uint4 rb[2]) {
  const int r = tid >> 1, kh = (tid & 1) * 16;
  const int row = n0 + r;
  if (row < NB) {
    const unsigned short* src = B + (size_t)row * EMB + k0 + kh;
    rb[0] = *(const uint4*)(src);
    rb[1] = *(const uint4*)(src + 8);
  } else {
    rb[0] = make_uint4(0, 0, 0, 0);
    rb[1] = make_uint4(0, 0, 0, 0);
  }
}
__device__ inline void storeBb(unsigned short* lds, int tid,
                               const uint4 rb[2]) {
  const int r = tid >> 1, kh = (tid & 1) * 16;
  unsigned short* dst = lds + r * LDSTR + kh;
  *(uint4*)(dst) = rb[0];
  *(uint4*)(dst + 8) = rb[1];
}

__device__ inline void mfma_step32(const unsigned short* ldsA,
                                   const unsigned short* ldsB, int wm, int wn,
                                   int lane, floatx4 acc[4][4]) {
  const unsigned short* ap =
      ldsA + (wm * 64 + (lane & 15)) * LDSTR + (lane >> 4) * 8;
  const unsigned short* bp =
      ldsB + (wn * 64 + (lane & 15)) * LDSTR + (lane >> 4) * 8;
  short8 af[4], bfr[4];
#pragma unroll
  for (int t = 0; t < 4; ++t) {
    af[t] = *(const short8*)(ap + t * 16 * LDSTR);
    bfr[t] = *(const short8*)(bp + t * 16 * LDSTR);
  }
#pragma unroll
  for (int mt = 0; mt < 4; ++mt)
#pragma unroll
    for (int nt = 0; nt < 4; ++nt)
      acc[mt][nt] = __builtin_amdgcn_mfma_f32_16x16x32_bf16(af[mt], bfr[nt],
                                                            acc[mt][nt], 0, 0, 0);
}

__device__ inline void gemm_loop32_f32A(const float* __restrict__ A, int M,
                                        int m0,
                                        const unsigned short* __restrict__ B,
                                        int NB, int n0, unsigned short* lds,
                                        int tid, int wm, int wn, int lane,
                                        floatx4 acc[4][4]) {
  unsigned short* bufA[2] = {lds, lds + 2 * TILEU};
  unsigned short* bufB[2] = {lds + TILEU, lds + 3 * TILEU};
  float4 sa[2][4];
  uint4 sb[2][2];
  loadA32(A, M, m0, 0, tid, sa[0]);
  loadBb(B, NB, n0, 0, tid, sb[0]);
  loadA32(A, M, m0, 32, tid, sa[1]);
  loadBb(B, NB, n0, 32, tid, sb[1]);
  storeA32(bufA[0], tid, sa[0]);
  storeBb(bufB[0], tid, sb[0]);
  __syncthreads();
#pragma unroll
  for (int k = 0; k < 8; ++k) {
    const int cur = k & 1, nxt = cur ^ 1;
    if (k + 2 < 8) {
      loadA32(A, M, m0, (k + 2) * 32, tid, sa[k & 1]);
      loadBb(B, NB, n0, (k + 2) * 32, tid, sb[k & 1]);
    }
    if (k + 1 < 8) {
      storeA32(bufA[nxt], tid, sa[(k + 1) & 1]);
      storeBb(bufB[nxt], tid, sb[(k + 1) & 1]);
    }
    mfma_step32(bufA[cur], bufB[cur], wm, wn, lane, acc);
    __syncthreads();
  }
}

// ---------------------------------------------------------------------------
// Fused K1+K2: blocks [0,832): value proj; [832,1408): offset/attn proj.
// Value-proj epilogue: stage 128x128 bf16 tile in LDS, then write vbh as
// coalesced 64-B (row, head) chunks: 4 lanes x dwordx4 per chunk, 8 passes.
// (Replaces 64 scattered 2-B stores per thread.)
// ---------------------------------------------------------------------------
__global__ __launch_bounds__(256, 2) void vqproj_kernel(
    const float* __restrict__ value, const unsigned short* __restrict__ Wt_val,
    const float* __restrict__ b_val, unsigned short* __restrict__ vbh,
    const float* __restrict__ query, const unsigned short* __restrict__ Wt_qcat,
    const float* __restrict__ refpts, const float* __restrict__ b_off,
    const float* __restrict__ b_attn, float* __restrict__ locbuf,
    float* __restrict__ awbuf) {
  __shared__ unsigned short lds[4 * TILEU];  // 40960 B: dbuf x (A,B)
  const int tid = threadIdx.x, lane = tid & 63, w = tid >> 6;
  const int wm = w >> 1, wn = w & 1;
  floatx4 acc[4][4];
  const floatx4 zero = {0.f, 0.f, 0.f, 0.f};
#pragma unroll
  for (int i2 = 0; i2 < 4; i2++)
#pragma unroll
    for (int j = 0; j < 4; j++) acc[i2][j] = zero;
  const int quad = lane >> 4, cl = lane & 15;

  if (blockIdx.x < 832) {
    const int chunk = blockIdx.x >> 4, i = blockIdx.x & 15;
    const int m0 = (chunk * 8 + (i & 7)) * 128;
    const int n0 = (i >> 3) * 128;
    gemm_loop32_f32A(value, MV, m0, Wt_val, 256, n0, lds, tid, wm, wn, lane,
                     acc);
    // ---- stage output tile (bf16, +bias) into LDS ----
    unsigned short* slds = lds;  // 128 x OSTR shorts = 34816 B, fits
#pragma unroll
    for (int mt = 0; mt < 4; ++mt) {
#pragma unroll
      for (int r = 0; r < 4; ++r) {
        const int rl = wm * 64 + mt * 16 + quad * 4 + r;
#pragma unroll
        for (int nt = 0; nt < 4; ++nt) {
          const int col = wn * 64 + nt * 16 + cl;
          slds[rl * OSTR + col] = bf16bits(acc[mt][nt][r] + b_val[n0 + col]);
        }
      }
    }
    __syncthreads();
    // ---- coalesced store: 512 chunks (128 rows x 4 heads) of 64 B ----
    const int piece = tid & 3;  // 16-B piece within chunk
#pragma unroll
    for (int p = 0; p < 8; ++p) {
      const int cid = p * 64 + (tid >> 2);
      const int rl = cid >> 2, hh = cid & 3;
      const int row = m0 + rl;
      if (row < MV) {
        const int b = row / NV, n = row - b * NV;
        const int h = (n0 >> 5) + hh;
        const uint4 v =
            *(const uint4*)(slds + rl * OSTR + hh * 32 + piece * 8);
        *(uint4*)(vbh + (((size_t)(b * NH + h)) * NV + n) * HD + piece * 8) = v;
      }
    }
  } else {
    const int bid = blockIdx.x - 832;
    const int chunk = bid / 24, i = bid % 24;
    const int m_idx = chunk * 8 + (i & 7);
    if (m_idx >= 188) return;
    const int m0 = m_idx * 128;
    const int n0 = (i >> 3) * 128;
    gemm_loop32_f32A(query, MQ, m0, Wt_qcat, 384, n0, lds, tid, wm, wn, lane,
                     acc);
    if (n0 < 256) {  // offset region
#pragma unroll
      for (int mt = 0; mt < 4; ++mt) {
#pragma unroll
        for (int r = 0; r < 4; ++r) {
          const int row = m0 + wm * 64 + mt * 16 + quad * 4 + r;
          if (row < MQ) {
#pragma unroll
            for (int nt = 0; nt < 4; ++nt) {
              const int c = n0 + wn * 64 + nt * 16 + cl;
              const int xy = c & 1, l = (c >> 3) & 3;
              const float dim = LVL_DIM[l];
              const float ref = refpts[(size_t)row * 8 + l * 2 + xy];
              locbuf[(size_t)row * 256 + c] =
                  ref * dim + acc[mt][nt][r] + b_off[c] - 0.5f;
            }
          }
        }
      }
    } else {  // attn region: raw logits, softmax fused into sample_kernel
#pragma unroll
      for (int mt = 0; mt < 4; ++mt) {
#pragma unroll
        for (int r = 0; r < 4; ++r) {
          const int row = m0 + wm * 64 + mt * 16 + quad * 4 + r;
          if (row < MQ) {
#pragma unroll
            for (int nt = 0; nt < 4; ++nt) {
              const int ca = wn * 64 + nt * 16 + cl;
              awbuf[(size_t)row * 128 + ca] = acc[mt][nt][r] + b_attn[ca];
            }
          }
        }
      }
    }
  }
}

// ---------------------------------------------------------------------------
// K3: bilinear sampling (+ fused softmax). 4 rows per wave, XCD-pinned.
// ---------------------------------------------------------------------------
__global__ __launch_bounds__(256, 4) void sample_kernel(
    const unsigned short* __restrict__ vbh, const float* __restrict__ locbuf,
    const float* __restrict__ awbuf, unsigned short* __restrict__ sampledb) {
  const int blk = blockIdx.x;
  const int t = blk >> 3;            // [0, 1500)
  const int quarter = t / 375;
  const int j = t - quarter * 375;   // [0, 375)
  const int slice = (blk & 7) * 4 + quarter;  // b*8 + h
  const int h = slice & 7;
  const int w = threadIdx.x >> 6;
  const int lane = threadIdx.x & 63;
  const int r0 = (slice >> 3) * NQ + j * 16 + w * 4;  // rows r0..r0+3
  const int g = lane >> 2;  // sample 0..15: l = g>>2, p = g&3
  const int d8 = lane & 3;  // dim octet
  const int l = g >> 2;

  const int W_ = (l < 2) ? ((l == 0) ? 100 : 50) : ((l == 2) ? 25 : 13);
  const int START = (l < 2) ? ((l == 0) ? 0 : 10000) : ((l == 2) ? 12500 : 13125);
  const unsigned int* base =
      (const unsigned int*)vbh + ((size_t)slice * NV + START) * 16 + d8 * 4;

  float acc[4][8];
#pragma unroll
  for (int rr = 0; rr < 4; ++rr) {
    const int row = r0 + rr;
    const float2 xy =
        *(const float2*)(locbuf + (size_t)row * 256 + h * 32 + g * 2);
    // fused softmax over g (16 logits per row,head)
    const float wl = awbuf[(size_t)row * 128 + h * 16 + g];
    float mx = wl;
    mx = fmaxf(mx, __shfl_xor(mx, 4));
    mx = fmaxf(mx, __shfl_xor(mx, 8));
    mx = fmaxf(mx, __shfl_xor(mx, 16));
    mx = fmaxf(mx, __shfl_xor(mx, 32));
    const float e = __expf(wl - mx);
    float ssum = e;
    ssum += __shfl_xor(ssum, 4);
    ssum += __shfl_xor(ssum, 8);
    ssum += __shfl_xor(ssum, 16);
    ssum += __shfl_xor(ssum, 32);
    const float wgt = e / ssum;

    const float fx = floorf(xy.x), fy = floorf(xy.y);
    const int x0 = (int)fx, y0 = (int)fy;
    const float wx1 = xy.x - fx, wy1 = xy.y - fy;
    const float wx0 = 1.f - wx1, wy0 = 1.f - wy1;
    const int x0c = min(max(x0, 0), W_ - 1), x1c = min(max(x0 + 1, 0), W_ - 1);
    const int y0c = min(max(y0, 0), W_ - 1), y1c = min(max(y0 + 1, 0), W_ - 1);
    const float mx0 = ((unsigned)x0 < (unsigned)W_) ? wx0 : 0.f;
    const float mx1 = ((unsigned)(x0 + 1) < (unsigned)W_) ? wx1 : 0.f;
    const float my0 = ((unsigned)y0 < (unsigned)W_) ? wy0 : 0.f;
    const float my1 = ((unsigned)(y0 + 1) < (unsigned)W_) ? wy1 : 0.f;
    const float wy0w = wgt * my0, wy1w = wgt * my1;
    const float w00 = wy0w * mx0, w01 = wy0w * mx1;
    const float w10 = wy1w * mx0, w11 = wy1w * mx1;

    const int rb0 = y0c * W_, rb1 = y1c * W_;
    const uint4 u00 = *(const uint4*)(base + (size_t)(rb0 + x0c) * 16);
    const uint4 u01 = *(const uint4*)(base + (size_t)(rb0 + x1c) * 16);
    const uint4 u10 = *(const uint4*)(base + (size_t)(rb1 + x0c) * 16);
    const uint4 u11 = *(const uint4*)(base + (size_t)(rb1 + x1c) * 16);
    const unsigned int* p00 = &u00.x;
    const unsigned int* p01 = &u01.x;
    const unsigned int* p10 = &u10.x;
    const unsigned int* p11 = &u11.x;
#pragma unroll
    for (int k = 0; k < 4; ++k) {
      acc[rr][2 * k] = w00 * bflo(p00[k]) + w01 * bflo(p01[k]) +
                       w10 * bflo(p10[k]) + w11 * bflo(p11[k]);
      acc[rr][2 * k + 1] = w00 * bfhi(p00[k]) + w01 * bfhi(p01[k]) +
                           w10 * bfhi(p10[k]) + w11 * bfhi(p11[k]);
    }
  }

  // reduce-scatter over the 16 sample-groups
  const bool b0 = (lane >> 2) & 1;
  const bool b1 = (lane >> 3) & 1;
  const bool b2 = (lane >> 4) & 1;
#pragma unroll
  for (int rr = 0; rr < 4; ++rr) {
    float* v = acc[rr];
#pragma unroll
    for (int jj = 0; jj < 4; ++jj) {
      float lo = v[jj], hi = v[jj + 4];
      float recv = __shfl_xor(b0 ? lo : hi, 4);
      v[jj] = (b0 ? hi : lo) + recv;
    }
#pragma unroll
    for (int jj = 0; jj < 2; ++jj) {
      float lo = v[jj], hi = v[jj + 2];
      float recv = __shfl_xor(b1 ? lo : hi, 8);
      v[jj] = (b1 ? hi : lo) + recv;
    }
    {
      float lo = v[0], hi = v[1];
      float recv = __shfl_xor(b2 ? lo : hi, 16);
      v[0] = (b2 ? hi : lo) + recv;
    }
    v[0] += __shfl_xor(v[0], 32);
  }

  const int dim = d8 * 8 + (b0 ? 4 : 0) + (b1 ? 2 : 0) + (b2 ? 1 : 0);
  const bool hi = (lane >= 32);
  const float v0 = hi ? acc[1][0] : acc[0][0];
  const float v1 = hi ? acc[3][0] : acc[2][0];
  const int row0 = r0 + (hi ? 1 : 0);
  const int row1 = r0 + 2 + (hi ? 1 : 0);
  sampledb[(size_t)row0 * EMB + h * 32 + dim] = bf16bits(v0);
  sampledb[(size_t)row1 * EMB + h * 32 + dim] = bf16bits(v1);
}

// ---------------------------------------------------------------------------
// K4: out = sampled @ W_out + b_out + query. 64x128 tiles, 2-wave blocks,
// grid 750 (5 blocks/CU resident by LDS): more resident parallelism than the
// old 384x256-thread version (1.5 blocks/CU of work).
// ---------------------------------------------------------------------------
#define OA 0                       // bufA0 offset (shorts)
#define OB (64 * LDSTR)            // bufB0
#define OA1 (192 * LDSTR)          // bufA1
#define OB1 (256 * LDSTR)          // bufB1
__global__ __launch_bounds__(128, 2) void oproj_kernel(
    const unsigned short* __restrict__ sampledb,
    const unsigned short* __restrict__ Wt, const float* __restrict__ b_out,
    const float* __restrict__ query, float* __restrict__ out) {
  __shared__ unsigned short lds[384 * LDSTR];  // 30720 B
  const int tid = threadIdx.x, lane = tid & 63, wn = tid >> 6;
  const int m0 = (blockIdx.x >> 1) * 64;
  const int n0 = (blockIdx.x & 1) * 128;
  floatx4 acc[4][4];
  const floatx4 zero = {0.f, 0.f, 0.f, 0.f};
#pragma unroll
  for (int i2 = 0; i2 < 4; i2++)
#pragma unroll
    for (int j = 0; j < 4; j++) acc[i2][j] = zero;

  unsigned short* bufA[2] = {lds + OA, lds + OA1};
  unsigned short* bufB[2] = {lds + OB, lds + OB1};
  // A: 64 rows x 32 k, 128 threads -> r=tid>>1, kh=(tid&1)*16 (32 B each)
  // B: 128 rows x 32 k, 128 threads -> full 64-B row each
  uint4 sa[2][2], sb[2][4];
#pragma unroll
  for (int s = 0; s < 2; ++s) {
    const int r = tid >> 1, kh = (tid & 1) * 16;
    const unsigned short* asrc =
        sampledb + (size_t)(m0 + r) * EMB + s * 32 + kh;
    sa[s][0] = *(const uint4*)(asrc);
    sa[s][1] = *(const uint4*)(asrc + 8);
    const unsigned short* bsrc = Wt + (size_t)(n0 + tid) * EMB + s * 32;
#pragma unroll
    for (int j = 0; j < 4; ++j) sb[s][j] = *(const uint4*)(bsrc + 8 * j);
  }
  {
    const int r = tid >> 1, kh = (tid & 1) * 16;
    *(uint4*)(bufA[0] + r * LDSTR + kh) = sa[0][0];
    *(uint4*)(bufA[0] + r * LDSTR + kh + 8) = sa[0][1];
#pragma unroll
    for (int j = 0; j < 4; ++j)
      *(uint4*)(bufB[0] + tid * LDSTR + 8 * j) = sb[0][j];
  }
  __syncthreads();
#pragma unroll
  for (int k = 0; k < 8; ++k) {
    const int cur = k & 1, nxt = cur ^ 1;
    if (k + 2 < 8) {
      const int r = tid >> 1, kh = (tid & 1) * 16;
      const unsigned short* asrc =
          sampledb + (size_t)(m0 + r) * EMB + (k + 2) * 32 + kh;
      sa[k & 1][0] = *(const uint4*)(asrc);
      sa[k & 1][1] = *(const uint4*)(asrc + 8);
      const unsigned short* bsrc = Wt + (size_t)(n0 + tid) * EMB + (k + 2) * 32;
#pragma unroll
      for (int j = 0; j < 4; ++j) sb[k & 1][j] = *(const uint4*)(bsrc + 8 * j);
    }
    if (k + 1 < 8) {
      const int r = tid >> 1, kh = (tid & 1) * 16;
      *(uint4*)(bufA[nxt] + r * LDSTR + kh) = sa[(k + 1) & 1][0];
      *(uint4*)(bufA[nxt] + r * LDSTR + kh + 8) = sa[(k + 1) & 1][1];
#pragma unroll
      for (int j = 0; j < 4; ++j)
        *(uint4*)(bufB[nxt] + tid * LDSTR + 8 * j) = sb[(k + 1) & 1][j];
    }
    mfma_step32(bufA[cur], bufB[cur], 0, wn, lane, acc);
    __syncthreads();
  }

  const int quad = lane >> 4, cl = lane & 15;
#pragma unroll
  for (int mt = 0; mt < 4; ++mt) {
#pragma unroll
    for (int r = 0; r < 4; ++r) {
      const int row = m0 + mt * 16 + quad * 4 + r;
#pragma unroll
      for (int nt = 0; nt < 4; ++nt) {
        const int c = n0 + wn * 64 + nt * 16 + cl;
        out[(size_t)row * EMB + c] =
            acc[mt][nt][r] + b_out[c] + query[(size_t)row * EMB + c];
      }
    }
  }
}

// ---------------------------------------------------------------------------
extern "C" void kernel_launch(void* const* d_in, const int* in_sizes, int n_in,
                              void* d_out, int out_size, void* d_ws,
                              size_t ws_size, hipStream_t stream) {
  const float* query  = (const float*)d_in[0];
  const float* value  = (const float*)d_in[1];
  const float* refpts = (const float*)d_in[2];
  const float* W_off  = (const float*)d_in[3];
  const float* b_off  = (const float*)d_in[4];
  const float* W_attn = (const float*)d_in[5];
  const float* b_attn = (const float*)d_in[6];
  const float* W_val  = (const float*)d_in[7];
  const float* b_val  = (const float*)d_in[8];
  const float* W_out  = (const float*)d_in[9];
  const float* b_out  = (const float*)d_in[10];
  float* out = (float*)d_out;

  char* ws = (char*)d_ws;
  unsigned short* vbh = (unsigned short*)ws;                   // 27,226,112 B
  float* locbuf = (float*)(ws + 27226112);                     // 24,576,000 B
  float* awbuf = (float*)(ws + 51802112);                      // 12,288,000 B
  unsigned short* sampledb = (unsigned short*)(ws + 64090112); // 12,288,000 B
  unsigned short* Wt_val = (unsigned short*)(ws + 76378112);   //    131,072 B
  unsigned short* Wt_qcat = (unsigned short*)(ws + 76509184);  //    196,608 B
  unsigned short* Wt_out = (unsigned short*)(ws + 76705792);   //    131,072 B

  wtrans_kernel<<<224, 256, 0, stream>>>(W_val, W_off, W_attn, W_out, Wt_val,
                                         Wt_qcat, Wt_out);
  vqproj_kernel<<<1408, 256, 0, stream>>>(value, Wt_val, b_val, vbh, query,
                                          Wt_qcat, refpts, b_off, b_attn,
                                          locbuf, awbuf);
  sample_kernel<<<12000, 256, 0, stream>>>(vbh, locbuf, awbuf, sampledb);
  oproj_kernel<<<750, 128, 0, stream>>>(sampledb, Wt_out, b_out, query, out);
}

// Round 6
// 231.836 us; speedup vs baseline: 1.1091x; 1.1091x over previous
//
#include <hip/hip_runtime.h>
#include <hip/hip_bf16.h>

#define BS 4
#define NQ 6000
#define NV 13294
#define NH 8
#define HD 32
#define EMB 256
#define MV (BS * NV)  // 53176
#define MQ (BS * NQ)  // 24000

typedef __attribute__((ext_vector_type(8))) short short8;
typedef __attribute__((ext_vector_type(4))) float floatx4;

__device__ __constant__ float LVL_DIM[4] = {100.f, 50.f, 25.f, 13.f};

__device__ inline unsigned short bf16bits(float f) {
  __hip_bfloat16 h = __float2bfloat16(f);
  return *reinterpret_cast<unsigned short*>(&h);
}
__device__ inline unsigned int pk2bf(float lo, float hi) {
  return (unsigned int)bf16bits(lo) | ((unsigned int)bf16bits(hi) << 16);
}
__device__ inline float bflo(unsigned int u) { return __uint_as_float(u << 16); }
__device__ inline float bfhi(unsigned int u) { return __uint_as_float(u & 0xffff0000u); }

// BK=32 tile rows: 32 bf16 = 64 B, padded to 80 B (LDSTR=40 shorts).
// 80 B is 16-byte aligned for every row -> real ds_read_b128/ds_write_b128.
// (R3 lesson: LDSTR=36 = 72 B broke 16B alignment -> split DS ops, +33 us.)
#define LDSTR 40
#define TILEU (128 * LDSTR)

// ---------------------------------------------------------------------------
// Coalesced tiled weight transpose + bf16 convert: Wt[n][k] = bf16(W[k][n]).
// ---------------------------------------------------------------------------
__global__ __launch_bounds__(256) void wtrans_kernel(
    const float* __restrict__ W_val, const float* __restrict__ W_off,
    const float* __restrict__ W_attn, const float* __restrict__ W_out,
    unsigned short* __restrict__ Wt_val, unsigned short* __restrict__ Wt_qcat,
    unsigned short* __restrict__ Wt_out) {
  __shared__ float tile[32][33];
  const int b = blockIdx.x;
  const int x = threadIdx.x & 31, ty = threadIdx.x >> 5;  // ty in [0,8)

  const float* src;
  unsigned short* dst;
  int k0, n0;  // src is [K=256][N], tile at (k0, n0); dst row = n, col = k
  if (b < 64) {
    src = W_val;
    dst = Wt_val;
    k0 = (b >> 3) * 32;
    n0 = (b & 7) * 32;
  } else if (b < 128) {
    const int bb = b - 64;
    src = W_off;
    dst = Wt_qcat;
    k0 = (bb >> 3) * 32;
    n0 = (bb & 7) * 32;
  } else if (b < 160) {
    const int bb = b - 128;  // W_attn: 256x128, tiles 8x4
    src = W_attn;
    dst = Wt_qcat + 256 * EMB;
    k0 = (bb >> 2) * 32;
    n0 = (bb & 3) * 32;
#pragma unroll
    for (int i = 0; i < 4; ++i)
      tile[ty + 8 * i][x] = src[(size_t)(k0 + ty + 8 * i) * 128 + n0 + x];
    __syncthreads();
#pragma unroll
    for (int i = 0; i < 4; ++i)
      dst[(size_t)(n0 + ty + 8 * i) * EMB + k0 + x] =
          bf16bits(tile[x][ty + 8 * i]);
    return;
  } else {
    const int bb = b - 160;
    src = W_out;
    dst = Wt_out;
    k0 = (bb >> 3) * 32;
    n0 = (bb & 7) * 32;
  }
#pragma unroll
  for (int i = 0; i < 4; ++i)
    tile[ty + 8 * i][x] = src[(size_t)(k0 + ty + 8 * i) * 256 + n0 + x];
  __syncthreads();
#pragma unroll
  for (int i = 0; i < 4; ++i)
    dst[(size_t)(n0 + ty + 8 * i) * EMB + k0 + x] = bf16bits(tile[x][ty + 8 * i]);
}

// ---------------------------------------------------------------------------
// MFMA-GEMM core: 128x128 tile, 4 waves (64x64 each), BK=32 (8 K-iters),
// double-buffered LDS, __syncthreads per K-iter, 2-deep register prefetch.
// ---------------------------------------------------------------------------
__device__ inline void loadA32(const float* __restrict__ A, int M, int m0,
                               int k0, int tid, float4 ra[4]) {
  const int r = tid >> 1, kh = (tid & 1) * 16;
  const int row = m0 + r;
  if (row < M) {
    const float* src = A + (size_t)row * EMB + k0 + kh;
#pragma unroll
    for (int j = 0; j < 4; ++j) ra[j] = *(const float4*)(src + 4 * j);
  } else {
#pragma unroll
    for (int j = 0; j < 4; ++j) ra[j] = make_float4(0.f, 0.f, 0.f, 0.f);
  }
}
__device__ inline void storeA32(unsigned short* lds, int tid,
                                const float4 ra[4]) {
  const int r = tid >> 1, kh = (tid & 1) * 16;
  unsigned short* dst = lds + r * LDSTR + kh;
  uint4 u0, u1;
  u0.x = pk2bf(ra[0].x, ra[0].y);
  u0.y = pk2bf(ra[0].z, ra[0].w);
  u0.z = pk2bf(ra[1].x, ra[1].y);
  u0.w = pk2bf(ra[1].z, ra[1].w);
  u1.x = pk2bf(ra[2].x, ra[2].y);
  u1.y = pk2bf(ra[2].z, ra[2].w);
  u1.z = pk2bf(ra[3].x, ra[3].y);
  u1.w = pk2bf(ra[3].z, ra[3].w);
  *(uint4*)(dst) = u0;
  *(uint4*)(dst + 8) = u1;
}
__device__ inline void loadBb(const unsigned short* __restrict__ B, int NB,
                              int n0, int k0, int tid, uint4 rb[2]) {
  const int r = tid >> 1, kh = (tid & 1) * 16;
  const int row = n0 + r;
  if (row < NB) {
    const unsigned short* src = B + (size_t)row * EMB + k0 + kh;
    rb[0] = *(const uint4*)(src);
    rb[1] = *(const uint4*)(src + 8);
  } else {
    rb[0] = make_uint4(0, 0, 0, 0);
    rb[1] = make_uint4(0, 0, 0, 0);
  }
}
__device__ inline void storeBb(unsigned short* lds, int tid,
                               const uint4 rb[2]) {
  const int r = tid >> 1, kh = (tid & 1) * 16;
  unsigned short* dst = lds + r * LDSTR + kh;
  *(uint4*)(dst) = rb[0];
  *(uint4*)(dst + 8) = rb[1];
}

__device__ inline void mfma_step32(const unsigned short* ldsA,
                                   const unsigned short* ldsB, int wm, int wn,
                                   int lane, floatx4 acc[4][4]) {
  const unsigned short* ap =
      ldsA + (wm * 64 + (lane & 15)) * LDSTR + (lane >> 4) * 8;
  const unsigned short* bp =
      ldsB + (wn * 64 + (lane & 15)) * LDSTR + (lane >> 4) * 8;
  short8 af[4], bfr[4];
#pragma unroll
  for (int t = 0; t < 4; ++t) {
    af[t] = *(const short8*)(ap + t * 16 * LDSTR);
    bfr[t] = *(const short8*)(bp + t * 16 * LDSTR);
  }
#pragma unroll
  for (int mt = 0; mt < 4; ++mt)
#pragma unroll
    for (int nt = 0; nt < 4; ++nt)
      acc[mt][nt] = __builtin_amdgcn_mfma_f32_16x16x32_bf16(af[mt], bfr[nt],
                                                            acc[mt][nt], 0, 0, 0);
}

__device__ inline void gemm_loop32_f32A(const float* __restrict__ A, int M,
                                        int m0,
                                        const unsigned short* __restrict__ B,
                                        int NB, int n0, unsigned short* lds,
                                        int tid, int wm, int wn, int lane,
                                        floatx4 acc[4][4]) {
  unsigned short* bufA[2] = {lds, lds + 2 * TILEU};
  unsigned short* bufB[2] = {lds + TILEU, lds + 3 * TILEU};
  float4 sa[2][4];
  uint4 sb[2][2];
  loadA32(A, M, m0, 0, tid, sa[0]);
  loadBb(B, NB, n0, 0, tid, sb[0]);
  loadA32(A, M, m0, 32, tid, sa[1]);
  loadBb(B, NB, n0, 32, tid, sb[1]);
  storeA32(bufA[0], tid, sa[0]);
  storeBb(bufB[0], tid, sb[0]);
  __syncthreads();
#pragma unroll
  for (int k = 0; k < 8; ++k) {
    const int cur = k & 1, nxt = cur ^ 1;
    if (k + 2 < 8) {
      loadA32(A, M, m0, (k + 2) * 32, tid, sa[k & 1]);
      loadBb(B, NB, n0, (k + 2) * 32, tid, sb[k & 1]);
    }
    if (k + 1 < 8) {
      storeA32(bufA[nxt], tid, sa[(k + 1) & 1]);
      storeBb(bufB[nxt], tid, sb[(k + 1) & 1]);
    }
    mfma_step32(bufA[cur], bufB[cur], wm, wn, lane, acc);
    __syncthreads();
  }
}

__device__ inline void gemm_loop32_bf16A(const unsigned short* __restrict__ A,
                                         int M, int m0,
                                         const unsigned short* __restrict__ B,
                                         int NB, int n0, unsigned short* lds,
                                         int tid, int wm, int wn, int lane,
                                         floatx4 acc[4][4]) {
  unsigned short* bufA[2] = {lds, lds + 2 * TILEU};
  unsigned short* bufB[2] = {lds + TILEU, lds + 3 * TILEU};
  uint4 sa[2][2], sb[2][2];
  loadBb(A, M, m0, 0, tid, sa[0]);
  loadBb(B, NB, n0, 0, tid, sb[0]);
  loadBb(A, M, m0, 32, tid, sa[1]);
  loadBb(B, NB, n0, 32, tid, sb[1]);
  storeBb(bufA[0], tid, sa[0]);
  storeBb(bufB[0], tid, sb[0]);
  __syncthreads();
#pragma unroll
  for (int k = 0; k < 8; ++k) {
    const int cur = k & 1, nxt = cur ^ 1;
    if (k + 2 < 8) {
      loadBb(A, M, m0, (k + 2) * 32, tid, sa[k & 1]);
      loadBb(B, NB, n0, (k + 2) * 32, tid, sb[k & 1]);
    }
    if (k + 1 < 8) {
      storeBb(bufA[nxt], tid, sa[(k + 1) & 1]);
      storeBb(bufB[nxt], tid, sb[(k + 1) & 1]);
    }
    mfma_step32(bufA[cur], bufB[cur], wm, wn, lane, acc);
    __syncthreads();
  }
}

// ---------------------------------------------------------------------------
// K1: value projection -> vbh (bf16, head-major). 832 blocks.
// (Split from the fused vqproj so rocprof's top-5 exposes sample/oproj.)
// ---------------------------------------------------------------------------
__global__ __launch_bounds__(256, 2) void vproj_kernel(
    const float* __restrict__ value, const unsigned short* __restrict__ Wt_val,
    const float* __restrict__ b_val, unsigned short* __restrict__ vbh) {
  __shared__ unsigned short lds[4 * TILEU];  // 40960 B: dbuf x (A,B)
  const int tid = threadIdx.x, lane = tid & 63, w = tid >> 6;
  const int wm = w >> 1, wn = w & 1;
  floatx4 acc[4][4];
  const floatx4 zero = {0.f, 0.f, 0.f, 0.f};
#pragma unroll
  for (int i2 = 0; i2 < 4; i2++)
#pragma unroll
    for (int j = 0; j < 4; j++) acc[i2][j] = zero;
  const int quad = lane >> 4, cl = lane & 15;

  const int chunk = blockIdx.x >> 4, i = blockIdx.x & 15;
  const int m0 = (chunk * 8 + (i & 7)) * 128;
  const int n0 = (i >> 3) * 128;
  gemm_loop32_f32A(value, MV, m0, Wt_val, 256, n0, lds, tid, wm, wn, lane,
                   acc);
#pragma unroll
  for (int mt = 0; mt < 4; ++mt) {
#pragma unroll
    for (int r = 0; r < 4; ++r) {
      const int row = m0 + wm * 64 + mt * 16 + quad * 4 + r;
      if (row < MV) {
        const int b = row / NV, n = row - b * NV;
#pragma unroll
        for (int nt = 0; nt < 4; ++nt) {
          const int c = n0 + wn * 64 + nt * 16 + cl;
          const int h = c >> 5, d = c & 31;
          vbh[(((size_t)(b * NH + h)) * NV + n) * HD + d] =
              bf16bits(acc[mt][nt][r] + b_val[c]);
        }
      }
    }
  }
}

// ---------------------------------------------------------------------------
// K2: query projection -> locbuf (sampling coords) + awbuf (raw logits).
// 576 blocks (564 active).
// ---------------------------------------------------------------------------
__global__ __launch_bounds__(256, 2) void qproj_kernel(
    const float* __restrict__ query, const unsigned short* __restrict__ Wt_qcat,
    const float* __restrict__ refpts, const float* __restrict__ b_off,
    const float* __restrict__ b_attn, float* __restrict__ locbuf,
    float* __restrict__ awbuf) {
  __shared__ unsigned short lds[4 * TILEU];
  const int tid = threadIdx.x, lane = tid & 63, w = tid >> 6;
  const int wm = w >> 1, wn = w & 1;
  floatx4 acc[4][4];
  const floatx4 zero = {0.f, 0.f, 0.f, 0.f};
#pragma unroll
  for (int i2 = 0; i2 < 4; i2++)
#pragma unroll
    for (int j = 0; j < 4; j++) acc[i2][j] = zero;
  const int quad = lane >> 4, cl = lane & 15;

  const int bid = blockIdx.x;
  const int chunk = bid / 24, i = bid % 24;
  const int m_idx = chunk * 8 + (i & 7);
  if (m_idx >= 188) return;
  const int m0 = m_idx * 128;
  const int n0 = (i >> 3) * 128;
  gemm_loop32_f32A(query, MQ, m0, Wt_qcat, 384, n0, lds, tid, wm, wn, lane,
                   acc);
  if (n0 < 256) {  // offset region
#pragma unroll
    for (int mt = 0; mt < 4; ++mt) {
#pragma unroll
      for (int r = 0; r < 4; ++r) {
        const int row = m0 + wm * 64 + mt * 16 + quad * 4 + r;
        if (row < MQ) {
#pragma unroll
          for (int nt = 0; nt < 4; ++nt) {
            const int c = n0 + wn * 64 + nt * 16 + cl;
            const int xy = c & 1, l = (c >> 3) & 3;
            const float dim = LVL_DIM[l];
            const float ref = refpts[(size_t)row * 8 + l * 2 + xy];
            locbuf[(size_t)row * 256 + c] =
                ref * dim + acc[mt][nt][r] + b_off[c] - 0.5f;
          }
        }
      }
    }
  } else {  // attn region: raw logits, softmax fused into sample_kernel
#pragma unroll
    for (int mt = 0; mt < 4; ++mt) {
#pragma unroll
      for (int r = 0; r < 4; ++r) {
        const int row = m0 + wm * 64 + mt * 16 + quad * 4 + r;
        if (row < MQ) {
#pragma unroll
          for (int nt = 0; nt < 4; ++nt) {
            const int ca = wn * 64 + nt * 16 + cl;
            awbuf[(size_t)row * 128 + ca] = acc[mt][nt][r] + b_attn[ca];
          }
        }
      }
    }
  }
}

// ---------------------------------------------------------------------------
// K3: bilinear sampling (+ fused softmax). 4 rows per wave, XCD-pinned.
// ---------------------------------------------------------------------------
__global__ __launch_bounds__(256, 4) void sample_kernel(
    const unsigned short* __restrict__ vbh, const float* __restrict__ locbuf,
    const float* __restrict__ awbuf, unsigned short* __restrict__ sampledb) {
  const int blk = blockIdx.x;
  const int t = blk >> 3;            // [0, 1500)
  const int quarter = t / 375;
  const int j = t - quarter * 375;   // [0, 375)
  const int slice = (blk & 7) * 4 + quarter;  // b*8 + h
  const int h = slice & 7;
  const int w = threadIdx.x >> 6;
  const int lane = threadIdx.x & 63;
  const int r0 = (slice >> 3) * NQ + j * 16 + w * 4;  // rows r0..r0+3
  const int g = lane >> 2;  // sample 0..15: l = g>>2, p = g&3
  const int d8 = lane & 3;  // dim octet
  const int l = g >> 2;

  const int W_ = (l < 2) ? ((l == 0) ? 100 : 50) : ((l == 2) ? 25 : 13);
  const int START = (l < 2) ? ((l == 0) ? 0 : 10000) : ((l == 2) ? 12500 : 13125);
  const unsigned int* base =
      (const unsigned int*)vbh + ((size_t)slice * NV + START) * 16 + d8 * 4;

  float acc[4][8];
#pragma unroll
  for (int rr = 0; rr < 4; ++rr) {
    const int row = r0 + rr;
    const float2 xy =
        *(const float2*)(locbuf + (size_t)row * 256 + h * 32 + g * 2);
    // fused softmax over g (16 logits per row,head)
    const float wl = awbuf[(size_t)row * 128 + h * 16 + g];
    float mx = wl;
    mx = fmaxf(mx, __shfl_xor(mx, 4));
    mx = fmaxf(mx, __shfl_xor(mx, 8));
    mx = fmaxf(mx, __shfl_xor(mx, 16));
    mx = fmaxf(mx, __shfl_xor(mx, 32));
    const float e = __expf(wl - mx);
    float ssum = e;
    ssum += __shfl_xor(ssum, 4);
    ssum += __shfl_xor(ssum, 8);
    ssum += __shfl_xor(ssum, 16);
    ssum += __shfl_xor(ssum, 32);
    const float wgt = e / ssum;

    const float fx = floorf(xy.x), fy = floorf(xy.y);
    const int x0 = (int)fx, y0 = (int)fy;
    const float wx1 = xy.x - fx, wy1 = xy.y - fy;
    const float wx0 = 1.f - wx1, wy0 = 1.f - wy1;
    const int x0c = min(max(x0, 0), W_ - 1), x1c = min(max(x0 + 1, 0), W_ - 1);
    const int y0c = min(max(y0, 0), W_ - 1), y1c = min(max(y0 + 1, 0), W_ - 1);
    const float mx0 = ((unsigned)x0 < (unsigned)W_) ? wx0 : 0.f;
    const float mx1 = ((unsigned)(x0 + 1) < (unsigned)W_) ? wx1 : 0.f;
    const float my0 = ((unsigned)y0 < (unsigned)W_) ? wy0 : 0.f;
    const float my1 = ((unsigned)(y0 + 1) < (unsigned)W_) ? wy1 : 0.f;
    const float wy0w = wgt * my0, wy1w = wgt * my1;
    const float w00 = wy0w * mx0, w01 = wy0w * mx1;
    const float w10 = wy1w * mx0, w11 = wy1w * mx1;

    const int rb0 = y0c * W_, rb1 = y1c * W_;
    const uint4 u00 = *(const uint4*)(base + (size_t)(rb0 + x0c) * 16);
    const uint4 u01 = *(const uint4*)(base + (size_t)(rb0 + x1c) * 16);
    const uint4 u10 = *(const uint4*)(base + (size_t)(rb1 + x0c) * 16);
    const uint4 u11 = *(const uint4*)(base + (size_t)(rb1 + x1c) * 16);
    const unsigned int* p00 = &u00.x;
    const unsigned int* p01 = &u01.x;
    const unsigned int* p10 = &u10.x;
    const unsigned int* p11 = &u11.x;
#pragma unroll
    for (int k = 0; k < 4; ++k) {
      acc[rr][2 * k] = w00 * bflo(p00[k]) + w01 * bflo(p01[k]) +
                       w10 * bflo(p10[k]) + w11 * bflo(p11[k]);
      acc[rr][2 * k + 1] = w00 * bfhi(p00[k]) + w01 * bfhi(p01[k]) +
                           w10 * bfhi(p10[k]) + w11 * bfhi(p11[k]);
    }
  }

  // reduce-scatter over the 16 sample-groups
  const bool b0 = (lane >> 2) & 1;
  const bool b1 = (lane >> 3) & 1;
  const bool b2 = (lane >> 4) & 1;
#pragma unroll
  for (int rr = 0; rr < 4; ++rr) {
    float* v = acc[rr];
#pragma unroll
    for (int jj = 0; jj < 4; ++jj) {
      float lo = v[jj], hi = v[jj + 4];
      float recv = __shfl_xor(b0 ? lo : hi, 4);
      v[jj] = (b0 ? hi : lo) + recv;
    }
#pragma unroll
    for (int jj = 0; jj < 2; ++jj) {
      float lo = v[jj], hi = v[jj + 2];
      float recv = __shfl_xor(b1 ? lo : hi, 8);
      v[jj] = (b1 ? hi : lo) + recv;
    }
    {
      float lo = v[0], hi = v[1];
      float recv = __shfl_xor(b2 ? lo : hi, 16);
      v[0] = (b2 ? hi : lo) + recv;
    }
    v[0] += __shfl_xor(v[0], 32);
  }

  const int dim = d8 * 8 + (b0 ? 4 : 0) + (b1 ? 2 : 0) + (b2 ? 1 : 0);
  const bool hi = (lane >= 32);
  const float v0 = hi ? acc[1][0] : acc[0][0];
  const float v1 = hi ? acc[3][0] : acc[2][0];
  const int row0 = r0 + (hi ? 1 : 0);
  const int row1 = r0 + 2 + (hi ? 1 : 0);
  sampledb[(size_t)row0 * EMB + h * 32 + dim] = bf16bits(v0);
  sampledb[(size_t)row1 * EMB + h * 32 + dim] = bf16bits(v1);
}

// ---------------------------------------------------------------------------
// K4: out = sampled @ W_out + b_out + query (residual fused). R4 version.
// ---------------------------------------------------------------------------
__global__ __launch_bounds__(256, 2) void oproj_kernel(
    const unsigned short* __restrict__ sampledb,
    const unsigned short* __restrict__ Wt, const float* __restrict__ b_out,
    const float* __restrict__ query, float* __restrict__ out) {
  __shared__ unsigned short lds[4 * TILEU];
  const int tid = threadIdx.x, lane = tid & 63, w = tid >> 6;
  const int wm = w >> 1, wn = w & 1;
  const int chunk = blockIdx.x >> 4, i = blockIdx.x & 15;
  const int m_idx = chunk * 8 + (i & 7);
  if (m_idx >= 188) return;
  const int m0 = m_idx * 128;
  const int n0 = (i >> 3) * 128;
  floatx4 acc[4][4];
  const floatx4 zero = {0.f, 0.f, 0.f, 0.f};
#pragma unroll
  for (int i2 = 0; i2 < 4; i2++)
#pragma unroll
    for (int j = 0; j < 4; j++) acc[i2][j] = zero;

  gemm_loop32_bf16A(sampledb, MQ, m0, Wt, 256, n0, lds, tid, wm, wn, lane,
                    acc);

  const int quad = lane >> 4, cl = lane & 15;
#pragma unroll
  for (int mt = 0; mt < 4; ++mt) {
#pragma unroll
    for (int r = 0; r < 4; ++r) {
      const int row = m0 + wm * 64 + mt * 16 + quad * 4 + r;
      if (row < MQ) {
#pragma unroll
        for (int nt = 0; nt < 4; ++nt) {
          const int c = n0 + wn * 64 + nt * 16 + cl;
          out[(size_t)row * EMB + c] =
              acc[mt][nt][r] + b_out[c] + query[(size_t)row * EMB + c];
        }
      }
    }
  }
}

// ---------------------------------------------------------------------------
extern "C" void kernel_launch(void* const* d_in, const int* in_sizes, int n_in,
                              void* d_out, int out_size, void* d_ws,
                              size_t ws_size, hipStream_t stream) {
  const float* query  = (const float*)d_in[0];
  const float* value  = (const float*)d_in[1];
  const float* refpts = (const float*)d_in[2];
  const float* W_off  = (const float*)d_in[3];
  const float* b_off  = (const float*)d_in[4];
  const float* W_attn = (const float*)d_in[5];
  const float* b_attn = (const float*)d_in[6];
  const float* W_val  = (const float*)d_in[7];
  const float* b_val  = (const float*)d_in[8];
  const float* W_out  = (const float*)d_in[9];
  const float* b_out  = (const float*)d_in[10];
  float* out = (float*)d_out;

  char* ws = (char*)d_ws;
  unsigned short* vbh = (unsigned short*)ws;                   // 27,226,112 B
  float* locbuf = (float*)(ws + 27226112);                     // 24,576,000 B
  float* awbuf = (float*)(ws + 51802112);                      // 12,288,000 B
  unsigned short* sampledb = (unsigned short*)(ws + 64090112); // 12,288,000 B
  unsigned short* Wt_val = (unsigned short*)(ws + 76378112);   //    131,072 B
  unsigned short* Wt_qcat = (unsigned short*)(ws + 76509184);  //    196,608 B
  unsigned short* Wt_out = (unsigned short*)(ws + 76705792);   //    131,072 B

  wtrans_kernel<<<224, 256, 0, stream>>>(W_val, W_off, W_attn, W_out, Wt_val,
                                         Wt_qcat, Wt_out);
  vproj_kernel<<<832, 256, 0, stream>>>(value, Wt_val, b_val, vbh);
  qproj_kernel<<<576, 256, 0, stream>>>(query, Wt_qcat, refpts, b_off, b_attn,
                                        locbuf, awbuf);
  sample_kernel<<<12000, 256, 0, stream>>>(vbh, locbuf, awbuf, sampledb);
  oproj_kernel<<<384, 256, 0, stream>>>(sampledb, Wt_out, b_out, query, out);
}